// Round 5
// baseline (1120.805 us; speedup 1.0000x reference)
//
#include <hip/hip_runtime.h>

#define S_LEN 2048
#define DMODEL 2048
#define NH 16
#define NKV 4
#define HD 128
#define NE 8
#define FF 2048
#define QKV_N 3072   // (H + 2*KV) * HD

typedef __attribute__((ext_vector_type(8))) short short8;
typedef __attribute__((ext_vector_type(4))) float f32x4;

__device__ inline unsigned short f2bf(float f) {
  unsigned int u = __builtin_bit_cast(unsigned int, f);
  u += 0x7fffu + ((u >> 16) & 1u);
  return (unsigned short)(u >> 16);
}
__device__ inline float bf2f(unsigned short h) {
  unsigned int u = ((unsigned int)h) << 16;
  return __builtin_bit_cast(float, u);
}
__device__ inline void split2(float v, unsigned short& h, unsigned short& l) {
  h = f2bf(v);
  l = f2bf(v - bf2f(h));
}

// ======== LDS tile: [128 rows][32 k] bf16, XOR-quad swizzle (verified r3/r4) ========
// element (row, k=8q+j) at row*32 + ((q ^ s(row))<<3) + j, s(row)=(row^(row>>2))&3.

__device__ inline void stage_rows(const unsigned short* __restrict__ src, int ld,
                                  long row0, int k0, unsigned short* dst) {
  int t = threadIdx.x;
  int r = t >> 2, q = t & 3;
  int s = (r ^ (r >> 2)) & 3;
  uint4 v0 = *(const uint4*)(src + (size_t)(row0 + r) * ld + k0 + q * 8);
  uint4 v1 = *(const uint4*)(src + (size_t)(row0 + r + 64) * ld + k0 + q * 8);
  *(uint4*)(dst + r * 32 + ((q ^ s) << 3)) = v0;
  *(uint4*)(dst + (r + 64) * 32 + ((q ^ s) << 3)) = v1;
}

__device__ inline void loadA2_rows(const unsigned short* __restrict__ src, int ld,
                                   long row0, int k0, uint4 va[2]) {
  int t = threadIdx.x;
  int r = t >> 2, q = t & 3;
  va[0] = *(const uint4*)(src + (size_t)(row0 + r) * ld + k0 + q * 8);
  va[1] = *(const uint4*)(src + (size_t)(row0 + r + 64) * ld + k0 + q * 8);
}
__device__ inline void loadA2_g(const unsigned short* __restrict__ src, int ld,
                                const int* __restrict__ toks, int nvalid, int k0,
                                uint4 va[2]) {
  int t = threadIdx.x;
  int r = t >> 2, q = t & 3;
#pragma unroll
  for (int rr = 0; rr < 2; rr++) {
    int row = r + rr * 64;
    uint4 v = make_uint4(0, 0, 0, 0);
    if (row < nvalid) v = *(const uint4*)(src + (size_t)toks[row] * ld + k0 + q * 8);
    va[rr] = v;
  }
}
__device__ inline void writeA2(const uint4 va[2], unsigned short* dst) {
  int t = threadIdx.x;
  int r = t >> 2, q = t & 3;
  int s = (r ^ (r >> 2)) & 3;
  *(uint4*)(dst + r * 32 + ((q ^ s) << 3)) = va[0];
  *(uint4*)(dst + (r + 64) * 32 + ((q ^ s) << 3)) = va[1];
}

// ---- async chunk staging: 8 KB pre-swizzled chunk -> LDS, verbatim ----
__device__ inline void gload16(const void* g, void* l) {
  __builtin_amdgcn_global_load_lds((const __attribute__((address_space(1))) unsigned int*)g,
                                   (__attribute__((address_space(3))) unsigned int*)l,
                                   16, 0, 0);
}
__device__ inline void stageB_chunk(const unsigned short* __restrict__ chunk,
                                    unsigned short* __restrict__ lds) {
  int w = threadIdx.x >> 6, l = threadIdx.x & 63;
  const unsigned short* s = chunk + w * 1024 + l * 8;   // 2 KB per wave
  unsigned short* d = lds + w * 1024;                   // wave-uniform LDS base
  gload16(s, d);
  gload16(s + 512, d + 512);
}

// ---------------- MFMA cores ----------------

__device__ inline void mma16(const unsigned short* As, const unsigned short* Bs,
                             int wr, int wc, f32x4 acc[4][4]) {
  int l = threadIdx.x & 63;
  int lr = l & 15, lg = l >> 4;
  int qoff = ((lg ^ ((lr ^ (lr >> 2)) & 3)) << 3);
  short8 a[4], b[4];
#pragma unroll
  for (int m = 0; m < 4; m++)
    a[m] = *(const short8*)(As + (wr + m * 16 + lr) * 32 + qoff);
#pragma unroll
  for (int n = 0; n < 4; n++)
    b[n] = *(const short8*)(Bs + (wc + n * 16 + lr) * 32 + qoff);
#pragma unroll
  for (int m = 0; m < 4; m++)
#pragma unroll
    for (int n = 0; n < 4; n++)
      acc[m][n] = __builtin_amdgcn_mfma_f32_16x16x32_bf16(a[m], b[n], acc[m][n], 0, 0, 0);
}

__device__ inline void mma16_split_reg(const unsigned short* Ash, const unsigned short* Asl,
                                       const unsigned short* Bsh, const unsigned short* Bsl,
                                       int wr, int wc, f32x4 acc[4][4]) {
  int l = threadIdx.x & 63;
  int lr = l & 15, lg = l >> 4;
  int qoff = ((lg ^ ((lr ^ (lr >> 2)) & 3)) << 3);
  short8 ah[4], al[4], bh[4], bl[4];
#pragma unroll
  for (int m = 0; m < 4; m++) {
    ah[m] = *(const short8*)(Ash + (wr + m * 16 + lr) * 32 + qoff);
    al[m] = *(const short8*)(Asl + (wr + m * 16 + lr) * 32 + qoff);
  }
#pragma unroll
  for (int n = 0; n < 4; n++) {
    bh[n] = *(const short8*)(Bsh + (wc + n * 16 + lr) * 32 + qoff);
    bl[n] = *(const short8*)(Bsl + (wc + n * 16 + lr) * 32 + qoff);
  }
#pragma unroll
  for (int m = 0; m < 4; m++)
#pragma unroll
    for (int n = 0; n < 4; n++) {
      acc[m][n] = __builtin_amdgcn_mfma_f32_16x16x32_bf16(ah[m], bh[n], acc[m][n], 0, 0, 0);
      acc[m][n] = __builtin_amdgcn_mfma_f32_16x16x32_bf16(ah[m], bl[n], acc[m][n], 0, 0, 0);
      acc[m][n] = __builtin_amdgcn_mfma_f32_16x16x32_bf16(al[m], bh[n], acc[m][n], 0, 0, 0);
    }
}

// ---------------- pack kernels: f32 [K][N] -> pre-swizzled 8KB bf16 chunks ----------------
// chunk index ((z*nc + c)*64 + kt); within chunk, ushort pos n*32+qp*8+j holds
// element (n, k = 8*(qp ^ s(n)) + j) of the (c,kt) tile — the exact LDS image.

__global__ __launch_bounds__(256) void k_pack1(const float* __restrict__ src, long ld,
                                               long zs, int nc,
                                               unsigned short* __restrict__ dst) {
  __shared__ float tile[32][132];
  const float* S = src + (long)blockIdx.z * zs;
  int c = blockIdx.x, t = threadIdx.x;
  for (int i = 0; i < 4; i++) {
    int kt = blockIdx.y * 4 + i;
    long k0 = (long)kt * 32, n0 = (long)c * 128;
    {
      int k = t >> 3, nn = (t & 7) * 16;
      const float4* p = (const float4*)(S + (k0 + k) * ld + n0 + nn);
#pragma unroll
      for (int j = 0; j < 4; j++) *(float4*)&tile[k][nn + j * 4] = p[j];
    }
    __syncthreads();
    size_t cbase = ((size_t)(blockIdx.z * nc + c) * 64 + kt) * 4096;
#pragma unroll
    for (int uu = 0; uu < 2; uu++) {
      int u = t * 2 + uu;
      int n = u >> 2, qp = u & 3;
      int q = qp ^ ((n ^ (n >> 2)) & 3);
      unsigned short hb[8] __attribute__((aligned(16)));
#pragma unroll
      for (int j = 0; j < 8; j++) hb[j] = f2bf(tile[8 * q + j][n]);
      *(uint4*)(dst + cbase + u * 8) = *(const uint4*)hb;
    }
    __syncthreads();
  }
}

__global__ __launch_bounds__(256) void k_pack2(const float* __restrict__ src, long ld,
                                               long zs, int nc,
                                               unsigned short* __restrict__ dh,
                                               unsigned short* __restrict__ dl) {
  __shared__ float tile[32][132];
  const float* S = src + (long)blockIdx.z * zs;
  int c = blockIdx.x, t = threadIdx.x;
  for (int i = 0; i < 4; i++) {
    int kt = blockIdx.y * 4 + i;
    long k0 = (long)kt * 32, n0 = (long)c * 128;
    {
      int k = t >> 3, nn = (t & 7) * 16;
      const float4* p = (const float4*)(S + (k0 + k) * ld + n0 + nn);
#pragma unroll
      for (int j = 0; j < 4; j++) *(float4*)&tile[k][nn + j * 4] = p[j];
    }
    __syncthreads();
    size_t cbase = ((size_t)(blockIdx.z * nc + c) * 64 + kt) * 4096;
#pragma unroll
    for (int uu = 0; uu < 2; uu++) {
      int u = t * 2 + uu;
      int n = u >> 2, qp = u & 3;
      int q = qp ^ ((n ^ (n >> 2)) & 3);
      unsigned short hb[8] __attribute__((aligned(16)));
      unsigned short lb[8] __attribute__((aligned(16)));
#pragma unroll
      for (int j = 0; j < 8; j++) split2(tile[8 * q + j][n], hb[j], lb[j]);
      *(uint4*)(dh + cbase + u * 8) = *(const uint4*)hb;
      *(uint4*)(dl + cbase + u * 8) = *(const uint4*)lb;
    }
    __syncthreads();
  }
}

// ---------------- attention-path GEMMs (fp32-emulated) ----------------

__global__ __launch_bounds__(256) void k_qkv_s(const unsigned short* __restrict__ Ah,
                                               const unsigned short* __restrict__ Al,
                                               const unsigned short* __restrict__ BPh,
                                               const unsigned short* __restrict__ BPl,
                                               float* __restrict__ C) {
  __shared__ unsigned short Ash[128 * 32], Asl[128 * 32], Bsh[128 * 32], Bsl[128 * 32];
  int row0 = blockIdx.y * 128;
  size_t cb = (size_t)blockIdx.x * 64 * 4096;
  int w = threadIdx.x >> 6;
  int wr = (w >> 1) * 64, wc = (w & 1) * 64;
  f32x4 acc[4][4] = {};
  for (int kt = 0; kt < 64; kt++) {
    __syncthreads();
    stage_rows(Ah, DMODEL, row0, kt * 32, Ash);
    stage_rows(Al, DMODEL, row0, kt * 32, Asl);
    stageB_chunk(BPh + cb + (size_t)kt * 4096, Bsh);
    stageB_chunk(BPl + cb + (size_t)kt * 4096, Bsl);
    __syncthreads();
    mma16_split_reg(Ash, Asl, Bsh, Bsl, wr, wc, acc);
  }
  int col0 = blockIdx.x * 128;
  int l = threadIdx.x & 63;
  int er = wr + ((l >> 4) << 2), ec = wc + (l & 15);
#pragma unroll
  for (int m = 0; m < 4; m++)
#pragma unroll
    for (int n = 0; n < 4; n++)
#pragma unroll
      for (int r = 0; r < 4; r++) {
        float v = acc[m][n][r];
        v = fminf(fmaxf(v, -8.f), 8.f);
        C[(size_t)(row0 + er + m * 16 + r) * QKV_N + col0 + ec + n * 16] = v;
      }
}

__global__ __launch_bounds__(256) void k_qk_s(const unsigned short* __restrict__ qh,
                                              const unsigned short* __restrict__ ql,
                                              const unsigned short* __restrict__ kh,
                                              const unsigned short* __restrict__ kl,
                                              unsigned short* __restrict__ Sh,
                                              unsigned short* __restrict__ Sl, int hbase) {
  if ((int)blockIdx.x > (int)blockIdx.y) return;
  int z = blockIdx.z;
  int h = hbase + z;
  const unsigned short* Ah = qh + (size_t)h * S_LEN * HD;
  const unsigned short* Al = ql + (size_t)h * S_LEN * HD;
  const unsigned short* Bh = kh + (size_t)(h >> 2) * S_LEN * HD;
  const unsigned short* Bl = kl + (size_t)(h >> 2) * S_LEN * HD;
  __shared__ unsigned short Ash[128 * 32], Asl[128 * 32], Bsh[128 * 32], Bsl[128 * 32];
  int row0 = blockIdx.y * 128, col0 = blockIdx.x * 128;
  int w = threadIdx.x >> 6;
  int wr = (w >> 1) * 64, wc = (w & 1) * 64;
  f32x4 acc[4][4] = {};
  for (int k0 = 0; k0 < HD; k0 += 32) {
    __syncthreads();
    stage_rows(Ah, HD, row0, k0, Ash);
    stage_rows(Al, HD, row0, k0, Asl);
    stage_rows(Bh, HD, col0, k0, Bsh);
    stage_rows(Bl, HD, col0, k0, Bsl);
    __syncthreads();
    mma16_split_reg(Ash, Asl, Bsh, Bsl, wr, wc, acc);
  }
  const float scale = 0.08838834764831845f;  // 1/sqrt(128)
  int l = threadIdx.x & 63;
  int er = wr + ((l >> 4) << 2), ec = wc + (l & 15);
#pragma unroll
  for (int m = 0; m < 4; m++)
#pragma unroll
    for (int n = 0; n < 4; n++)
#pragma unroll
      for (int r = 0; r < 4; r++) {
        float v = acc[m][n][r] * scale;
        size_t idx = ((size_t)z * S_LEN + row0 + er + m * 16 + r) * S_LEN + col0 + ec + n * 16;
        unsigned short hh, ll;
        split2(v, hh, ll);
        Sh[idx] = hh; Sl[idx] = ll;
      }
}

__global__ __launch_bounds__(256) void k_sm_s(unsigned short* __restrict__ Sh,
                                              unsigned short* __restrict__ Sl) {
  int q = blockIdx.x, z = blockIdx.y;
  size_t base = ((size_t)z * S_LEN + q) * S_LEN;
  int t = threadIdx.x;
  uint4 hv = ((const uint4*)(Sh + base))[t];
  uint4 lv = ((const uint4*)(Sl + base))[t];
  unsigned short* hp = (unsigned short*)&hv;
  unsigned short* lp = (unsigned short*)&lv;
  float v[8];
  float mx = -3.4e38f;
#pragma unroll
  for (int j = 0; j < 8; j++) {
    int c = t * 8 + j;
    float x = bf2f(hp[j]) + bf2f(lp[j]);
    v[j] = x;
    if (c <= q) mx = fmaxf(mx, x);
  }
#pragma unroll
  for (int o = 32; o; o >>= 1) mx = fmaxf(mx, __shfl_down(mx, o));
  __shared__ float red[8];
  int wid = t >> 6;
  if ((t & 63) == 0) red[wid] = mx;
  __syncthreads();
  if (t == 0) red[4] = fmaxf(fmaxf(red[0], red[1]), fmaxf(red[2], red[3]));
  __syncthreads();
  mx = red[4];
  float s = 0.f;
#pragma unroll
  for (int j = 0; j < 8; j++) {
    float e = (t * 8 + j <= q) ? expf(v[j] - mx) : 0.f;
    v[j] = e; s += e;
  }
#pragma unroll
  for (int o = 32; o; o >>= 1) s += __shfl_down(s, o);
  if ((t & 63) == 0) red[wid] = s;
  __syncthreads();
  if (t == 0) red[5] = red[0] + red[1] + red[2] + red[3];
  __syncthreads();
  float inv = 1.f / red[5];
#pragma unroll
  for (int j = 0; j < 8; j++) split2(v[j] * inv, hp[j], lp[j]);
  ((uint4*)(Sh + base))[t] = hv;
  ((uint4*)(Sl + base))[t] = lv;
}

// PV partials; B = packed V chunks (per kv head, nc=1)
__global__ __launch_bounds__(256) void k_pv(const unsigned short* __restrict__ Ph,
                                            const unsigned short* __restrict__ Pl,
                                            const unsigned short* __restrict__ vPh,
                                            const unsigned short* __restrict__ vPl,
                                            float* __restrict__ pvp, int hbase) {
  int kc = blockIdx.x, rt = blockIdx.y, z = blockIdx.z;
  int Keff = (rt + 1) * 128;
  int kbeg = kc * 512;
  if (kbeg >= Keff) return;
  int kend = min(kbeg + 512, Keff);
  int h = hbase + z;
  const unsigned short* Ah = Ph + (size_t)z * S_LEN * S_LEN;
  const unsigned short* Al = Pl + (size_t)z * S_LEN * S_LEN;
  size_t cb = (size_t)(h >> 2) * 64 * 4096;
  __shared__ unsigned short Ash[128 * 32], Asl[128 * 32], Bsh[128 * 32], Bsl[128 * 32];
  int row0 = rt * 128;
  int w = threadIdx.x >> 6;
  int wr = (w >> 1) * 64, wc = (w & 1) * 64;
  f32x4 acc[4][4] = {};
  for (int k0 = kbeg; k0 < kend; k0 += 32) {
    int kt = k0 >> 5;
    __syncthreads();
    stage_rows(Ah, S_LEN, row0, k0, Ash);
    stage_rows(Al, S_LEN, row0, k0, Asl);
    stageB_chunk(vPh + cb + (size_t)kt * 4096, Bsh);
    stageB_chunk(vPl + cb + (size_t)kt * 4096, Bsl);
    __syncthreads();
    mma16_split_reg(Ash, Asl, Bsh, Bsl, wr, wc, acc);
  }
  int l = threadIdx.x & 63;
  int er = wr + ((l >> 4) << 2), ec = wc + (l & 15);
  float* dst = pvp + ((size_t)z * 4 + kc) * S_LEN * HD;
#pragma unroll
  for (int m = 0; m < 4; m++)
#pragma unroll
    for (int n = 0; n < 4; n++)
#pragma unroll
      for (int r = 0; r < 4; r++)
        dst[(size_t)(row0 + er + m * 16 + r) * HD + ec + n * 16] = acc[m][n][r];
}

__global__ __launch_bounds__(256) void k_pvred(const float* __restrict__ pvp,
                                               unsigned short* __restrict__ ath,
                                               unsigned short* __restrict__ atl, int hbase) {
  int idx = blockIdx.x * 256 + threadIdx.x;
  int c4 = idx & 31;
  int row = (idx >> 5) & (S_LEN - 1);
  int z = idx >> 16;
  int nkc = (row >> 9) + 1;
  const float* src = pvp + (size_t)z * 4 * S_LEN * HD + (size_t)row * HD + c4 * 4;
  float a0 = 0.f, a1 = 0.f, a2 = 0.f, a3 = 0.f;
  for (int j = 0; j < nkc; j++) {
    float4 p = *(const float4*)(src + (size_t)j * S_LEN * HD);
    a0 += p.x; a1 += p.y; a2 += p.z; a3 += p.w;
  }
  size_t o = (size_t)row * DMODEL + (size_t)(hbase + z) * HD + c4 * 4;
  unsigned short hh, ll;
  split2(a0, hh, ll); ath[o] = hh; atl[o] = ll;
  split2(a1, hh, ll); ath[o + 1] = hh; atl[o + 1] = ll;
  split2(a2, hh, ll); ath[o + 2] = hh; atl[o + 2] = ll;
  split2(a3, hh, ll); ath[o + 3] = hh; atl[o + 3] = ll;
}

__global__ __launch_bounds__(256) void k_wo_s(const unsigned short* __restrict__ Ah,
                                              const unsigned short* __restrict__ Al,
                                              const unsigned short* __restrict__ BPh,
                                              const unsigned short* __restrict__ BPl,
                                              const float* __restrict__ resid,
                                              float* __restrict__ x1) {
  __shared__ unsigned short Ash[128 * 32], Asl[128 * 32], Bsh[128 * 32], Bsl[128 * 32];
  int row0 = blockIdx.y * 128;
  size_t cb = (size_t)blockIdx.x * 64 * 4096;
  int w = threadIdx.x >> 6;
  int wr = (w >> 1) * 64, wc = (w & 1) * 64;
  f32x4 acc[4][4] = {};
  for (int kt = 0; kt < 64; kt++) {
    __syncthreads();
    stage_rows(Ah, DMODEL, row0, kt * 32, Ash);
    stage_rows(Al, DMODEL, row0, kt * 32, Asl);
    stageB_chunk(BPh + cb + (size_t)kt * 4096, Bsh);
    stageB_chunk(BPl + cb + (size_t)kt * 4096, Bsl);
    __syncthreads();
    mma16_split_reg(Ash, Asl, Bsh, Bsl, wr, wc, acc);
  }
  int col0 = blockIdx.x * 128;
  int l = threadIdx.x & 63;
  int er = wr + ((l >> 4) << 2), ec = wc + (l & 15);
#pragma unroll
  for (int m = 0; m < 4; m++)
#pragma unroll
    for (int n = 0; n < 4; n++)
#pragma unroll
      for (int r = 0; r < 4; r++) {
        size_t idx = (size_t)(row0 + er + m * 16 + r) * DMODEL + col0 + ec + n * 16;
        x1[idx] = resid[idx] + acc[m][n][r];
      }
}

// ---------------- MoE GEMMs: packed-chunk B + reg-prefetched gathered A ----------------

__global__ __launch_bounds__(256) void k_moe_w1(const unsigned short* __restrict__ h2b,
                                                const unsigned short* __restrict__ wP,
                                                const int* __restrict__ off,
                                                const int* __restrict__ ptok,
                                                const int* __restrict__ meta,
                                                float* __restrict__ a1) {
  int ty = blockIdx.y;
  if (ty >= meta[25]) return;
  int tt = meta[26 + ty];
  int e = tt & 7, m0 = tt >> 3;
  int nvalid = min(128, meta[e] - m0);
  const int* toks = ptok + off[e] + m0;
  const unsigned short* Bb = wP + (size_t)(e * 16 + blockIdx.x) * 64 * 4096;
  __shared__ unsigned short As[128 * 32], Bs[128 * 32];
  int w = threadIdx.x >> 6;
  int wr = (w >> 1) * 64, wc = (w & 1) * 64;
  uint4 va[2];
  loadA2_g(h2b, DMODEL, toks, nvalid, 0, va);
  f32x4 acc[4][4] = {};
  for (int kt = 0; kt < 64; kt++) {
    __syncthreads();
    writeA2(va, As);
    stageB_chunk(Bb + (size_t)kt * 4096, Bs);
    if (kt + 1 < 64) loadA2_g(h2b, DMODEL, toks, nvalid, (kt + 1) * 32, va);
    __syncthreads();
    mma16(As, Bs, wr, wc, acc);
  }
  int col0 = blockIdx.x * 128;
  int l = threadIdx.x & 63;
  int er = wr + ((l >> 4) << 2), ec = wc + (l & 15);
  size_t gbase = (size_t)off[e] + m0;
#pragma unroll
  for (int m = 0; m < 4; m++)
#pragma unroll
    for (int n = 0; n < 4; n++)
#pragma unroll
      for (int r = 0; r < 4; r++) {
        int rl = er + m * 16 + r;
        if (rl < nvalid)
          a1[(gbase + rl) * FF + col0 + ec + n * 16] = acc[m][n][r];
      }
}

__global__ __launch_bounds__(256) void k_moe_v1g(const unsigned short* __restrict__ h2b,
                                                 const unsigned short* __restrict__ wP,
                                                 const float* __restrict__ a1,
                                                 const int* __restrict__ off,
                                                 const int* __restrict__ ptok,
                                                 const int* __restrict__ meta,
                                                 unsigned short* __restrict__ g) {
  int ty = blockIdx.y;
  if (ty >= meta[25]) return;
  int tt = meta[26 + ty];
  int e = tt & 7, m0 = tt >> 3;
  int nvalid = min(128, meta[e] - m0);
  const int* toks = ptok + off[e] + m0;
  const unsigned short* Bb = wP + (size_t)(e * 16 + blockIdx.x) * 64 * 4096;
  __shared__ unsigned short As[128 * 32], Bs[128 * 32];
  int w = threadIdx.x >> 6;
  int wr = (w >> 1) * 64, wc = (w & 1) * 64;
  uint4 va[2];
  loadA2_g(h2b, DMODEL, toks, nvalid, 0, va);
  f32x4 acc[4][4] = {};
  for (int kt = 0; kt < 64; kt++) {
    __syncthreads();
    writeA2(va, As);
    stageB_chunk(Bb + (size_t)kt * 4096, Bs);
    if (kt + 1 < 64) loadA2_g(h2b, DMODEL, toks, nvalid, (kt + 1) * 32, va);
    __syncthreads();
    mma16(As, Bs, wr, wc, acc);
  }
  int col0 = blockIdx.x * 128;
  int l = threadIdx.x & 63;
  int er = wr + ((l >> 4) << 2), ec = wc + (l & 15);
  size_t gbase = (size_t)off[e] + m0;
#pragma unroll
  for (int m = 0; m < 4; m++)
#pragma unroll
    for (int n = 0; n < 4; n++)
#pragma unroll
      for (int r = 0; r < 4; r++) {
        int rl = er + m * 16 + r;
        if (rl < nvalid) {
          size_t idx = (gbase + rl) * FF + col0 + ec + n * 16;
          float av = a1[idx];
          float s = av / (1.f + expf(-av));
          g[idx] = f2bf(s * acc[m][n][r]);
        }
      }
}

__global__ __launch_bounds__(256) void k_moe2(const unsigned short* __restrict__ g,
                                              const unsigned short* __restrict__ wP,
                                              const int* __restrict__ off,
                                              const int* __restrict__ ptok,
                                              const float* __restrict__ pw,
                                              const int* __restrict__ meta,
                                              float* __restrict__ y) {
  int ty = blockIdx.y;
  if (ty >= meta[25]) return;
  int tt = meta[26 + ty];
  int e = tt & 7, m0 = tt >> 3;
  int nvalid = min(128, meta[e] - m0);
  long pbase = (long)off[e] + m0;
  const unsigned short* Bb = wP + (size_t)(e * 16 + blockIdx.x) * 64 * 4096;
  __shared__ unsigned short As[128 * 32], Bs[128 * 32];
  int w = threadIdx.x >> 6;
  int wr = (w >> 1) * 64, wc = (w & 1) * 64;
  uint4 va[2];
  loadA2_rows(g, FF, pbase, 0, va);
  f32x4 acc[4][4] = {};
  for (int kt = 0; kt < 64; kt++) {
    __syncthreads();
    writeA2(va, As);
    stageB_chunk(Bb + (size_t)kt * 4096, Bs);
    if (kt + 1 < 64) loadA2_rows(g, FF, pbase, (kt + 1) * 32, va);
    __syncthreads();
    mma16(As, Bs, wr, wc, acc);
  }
  int col0 = blockIdx.x * 128;
  int l = threadIdx.x & 63;
  int er = wr + ((l >> 4) << 2), ec = wc + (l & 15);
#pragma unroll
  for (int m = 0; m < 4; m++)
#pragma unroll
    for (int n = 0; n < 4; n++)
#pragma unroll
      for (int r = 0; r < 4; r++) {
        int rl = er + m * 16 + r;
        if (rl < nvalid) {
          long p = pbase + rl;
          int tk = ptok[p];
          atomicAdd(&y[(size_t)tk * DMODEL + col0 + ec + n * 16], acc[m][n][r] * pw[p]);
        }
      }
}

// ---------------- small kernels ----------------

__global__ __launch_bounds__(256) void k_ln(const float* __restrict__ x,
                                            const float* __restrict__ w,
                                            unsigned short* __restrict__ obh,
                                            unsigned short* __restrict__ obl,
                                            float* __restrict__ of) {
  int row = blockIdx.x;
  const float* xr = x + (size_t)row * DMODEL;
  float s = 0.f, ss = 0.f;
  for (int c = threadIdx.x; c < DMODEL; c += 256) {
    float v = xr[c];
    s += v; ss += v * v;
  }
#pragma unroll
  for (int o = 32; o; o >>= 1) { s += __shfl_down(s, o); ss += __shfl_down(ss, o); }
  __shared__ float rs[4], rss[4], mu_s, inv_s;
  int wid = threadIdx.x >> 6;
  if ((threadIdx.x & 63) == 0) { rs[wid] = s; rss[wid] = ss; }
  __syncthreads();
  if (threadIdx.x == 0) {
    float S1 = rs[0] + rs[1] + rs[2] + rs[3];
    float S2 = rss[0] + rss[1] + rss[2] + rss[3];
    float mu = S1 / DMODEL;
    mu_s = mu;
    inv_s = rsqrtf(S2 / DMODEL - mu * mu + 1e-5f);
  }
  __syncthreads();
  float mu = mu_s, inv = inv_s;
  for (int c = threadIdx.x; c < DMODEL; c += 256) {
    float v = (xr[c] - mu) * inv * w[c];
    unsigned short hh, ll;
    split2(v, hh, ll);
    obh[(size_t)row * DMODEL + c] = hh;
    if (obl) obl[(size_t)row * DMODEL + c] = ll;
    if (of) of[(size_t)row * DMODEL + c] = v;
  }
}

__global__ void k_rope2(const float* __restrict__ qkv, unsigned short* __restrict__ qh,
                        unsigned short* __restrict__ ql, unsigned short* __restrict__ kh,
                        unsigned short* __restrict__ kl) {
  int t = blockIdx.x;
  int d = threadIdx.x;  // 0..63
  float pf = (float)pow(500000.0, (double)d * (1.0 / 64.0));
  float invf = 1.0f / pf;
  float ang = (float)t * invf;
  float cs = (float)cos((double)ang);
  float sn = (float)sin((double)ang);
  const float* row = qkv + (size_t)t * QKV_N;
  unsigned short hh, ll;
#pragma unroll
  for (int hq = 0; hq < NH; hq++) {
    float a = row[hq * HD + d], b = row[hq * HD + d + 64];
    size_t base = ((size_t)hq * S_LEN + t) * HD;
    split2(a * cs - b * sn, hh, ll); qh[base + d] = hh; ql[base + d] = ll;
    split2(b * cs + a * sn, hh, ll); qh[base + d + 64] = hh; ql[base + d + 64] = ll;
  }
#pragma unroll
  for (int kv = 0; kv < NKV; kv++) {
    float a = row[NH * HD + kv * HD + d], b = row[NH * HD + kv * HD + d + 64];
    size_t base = ((size_t)kv * S_LEN + t) * HD;
    split2(a * cs - b * sn, hh, ll); kh[base + d] = hh; kl[base + d] = ll;
    split2(b * cs + a * sn, hh, ll); kh[base + d + 64] = hh; kl[base + d + 64] = ll;
  }
}

__global__ __launch_bounds__(256) void k_router(const float* __restrict__ h2,
                                                const float* __restrict__ rw,
                                                int* __restrict__ topi,
                                                float* __restrict__ topw,
                                                int* __restrict__ cnt) {
  int t = blockIdx.x;
  __shared__ float hs[DMODEL];
  __shared__ float lg[NE];
  for (int c = threadIdx.x; c < DMODEL; c += 256) hs[c] = h2[(size_t)t * DMODEL + c];
  __syncthreads();
  int grp = threadIdx.x >> 5;
  int ln = threadIdx.x & 31;
  float p = 0.f;
  for (int c = ln; c < DMODEL; c += 32) p += hs[c] * rw[(size_t)grp * DMODEL + c];
#pragma unroll
  for (int o = 16; o; o >>= 1) p += __shfl_down(p, o, 32);
  if (ln == 0) lg[grp] = p;
  __syncthreads();
  if (threadIdx.x == 0) {
    float l0 = -3.4e38f; int i0 = 0;
    for (int e = 0; e < NE; e++)
      if (lg[e] > l0) { l0 = lg[e]; i0 = e; }
    float l1 = -3.4e38f; int i1 = 0;
    for (int e = 0; e < NE; e++)
      if (e != i0 && lg[e] > l1) { l1 = lg[e]; i1 = e; }
    float z = expf(l1 - l0);
    topi[t * 2] = i0; topi[t * 2 + 1] = i1;
    topw[t * 2] = 1.f / (1.f + z); topw[t * 2 + 1] = z / (1.f + z);
    atomicAdd(&cnt[i0], 1);
    atomicAdd(&cnt[i1], 1);
  }
}

__global__ void k_scan(int* __restrict__ meta) {
  if (threadIdx.x == 0 && blockIdx.x == 0) {
    int o = 0, nt = 0;
    for (int e = 0; e < NE; e++) {
      meta[16 + e] = o;
      for (int m0 = 0; m0 < meta[e]; m0 += 128) meta[26 + nt++] = (m0 << 3) | e;
      o += meta[e];
    }
    meta[24] = o;
    meta[25] = nt;
  }
}

__global__ void k_fill(const int* __restrict__ topi, const float* __restrict__ topw,
                       int* __restrict__ meta, int* __restrict__ ptok,
                       float* __restrict__ pw) {
  int t = blockIdx.x * blockDim.x + threadIdx.x;
  if (t >= S_LEN) return;
#pragma unroll
  for (int j = 0; j < 2; j++) {
    int e = topi[t * 2 + j];
    int p = atomicAdd(&meta[8 + e], 1);
    ptok[meta[16 + e] + p] = t;
    pw[meta[16 + e] + p] = topw[t * 2 + j];
  }
}

// out += y (in place; out holds x1)
__global__ void k_final(float* __restrict__ out, const float* __restrict__ y) {
  int i = blockIdx.x * blockDim.x + threadIdx.x;
  float4 a = ((const float4*)out)[i];
  float4 b = ((const float4*)y)[i];
  ((float4*)out)[i] = make_float4(a.x + b.x, a.y + b.y, a.z + b.z, a.w + b.w);
}

// ---------------- launch ----------------

extern "C" void kernel_launch(void* const* d_in, const int* in_sizes, int n_in,
                              void* d_out, int out_size, void* d_ws, size_t ws_size,
                              hipStream_t stream) {
  (void)in_sizes; (void)n_in; (void)out_size; (void)ws_size;
  const float* x = (const float*)d_in[0];
  const float* ln1w = (const float*)d_in[2];
  const float* ln2w = (const float*)d_in[3];
  const float* wqkv = (const float*)d_in[4];
  const float* wo = (const float*)d_in[5];
  const float* rw = (const float*)d_in[6];
  const float* w1 = (const float*)d_in[7];
  const float* v1 = (const float*)d_in[8];
  const float* w2 = (const float*)d_in[9];
  float* out = (float*)d_out;  // holds x1 after k_wo_s

  char* wsb = (char*)d_ws;
  const size_t MiB = 1u << 20;
  // ---- attention phase ----
  unsigned short* h1h = (unsigned short*)(wsb + 0 * MiB);      // 8
  unsigned short* h1l = (unsigned short*)(wsb + 8 * MiB);      // 8
  float* pvp = (float*)(wsb + 0 * MiB);                        // 16 (attn loop, over h1)
  float* qkvb = (float*)(wsb + 16 * MiB);                      // 24
  unsigned short* qh = (unsigned short*)(wsb + 40 * MiB);      // 8
  unsigned short* ql = (unsigned short*)(wsb + 48 * MiB);      // 8
  unsigned short* kh = (unsigned short*)(wsb + 56 * MiB);      // 2
  unsigned short* kl = (unsigned short*)(wsb + 58 * MiB);      // 2
  unsigned short* vPh = (unsigned short*)(wsb + 60 * MiB);     // 2 (packed V chunks)
  unsigned short* vPl = (unsigned short*)(wsb + 62 * MiB);     // 2
  unsigned short* Sh = (unsigned short*)(wsb + 64 * MiB);      // 32
  unsigned short* Sl = (unsigned short*)(wsb + 96 * MiB);      // 32
  unsigned short* ath = (unsigned short*)(wsb + 128 * MiB);    // 8
  unsigned short* atl = (unsigned short*)(wsb + 136 * MiB);    // 8
  unsigned short* wqkvPh = (unsigned short*)(wsb + 144 * MiB); // 12 (packed chunks)
  unsigned short* wqkvPl = (unsigned short*)(wsb + 156 * MiB); // 12
  unsigned short* woPh = (unsigned short*)(wsb + 168 * MiB);   // 8
  unsigned short* woPl = (unsigned short*)(wsb + 176 * MiB);   // 8
  // ---- MoE phase (over dead attention buffers) ----
  float* h2f = (float*)(wsb + 0 * MiB);                        // 16 (over pvp/h1)
  float* a1 = (float*)(wsb + 16 * MiB);                        // 40 (over qkvb/qh/ql)
  unsigned short* wP = (unsigned short*)(wsb + 64 * MiB);      // 64 (over Sh/Sl) shared pack buf
  unsigned short* g = (unsigned short*)(wsb + 128 * MiB);      // 20 (over ath/atl/wqkvPh)
  float* y = (float*)(wsb + 148 * MiB);                        // 16 (over wqkvP)
  unsigned short* h2b = (unsigned short*)(wsb + 164 * MiB);    // 8 (over wqkvPl/woPh)
  char* small = wsb + 185 * MiB;
  int* topi = (int*)small;
  float* topw = (float*)(small + 16384);
  int* ptok = (int*)(small + 32768);
  float* pw = (float*)(small + 49152);
  int* meta = (int*)(small + 65536);  // 128 ints

  // ---- pack attention weights ----
  k_pack2<<<dim3(QKV_N / 128, 16, 1), 256, 0, stream>>>(wqkv, QKV_N, 0, QKV_N / 128,
                                                        wqkvPh, wqkvPl);
  k_pack2<<<dim3(DMODEL / 128, 16, 1), 256, 0, stream>>>(wo, DMODEL, 0, DMODEL / 128,
                                                         woPh, woPl);

  // ---- attention sublayer (fp32-emulated) ----
  k_ln<<<S_LEN, 256, 0, stream>>>(x, ln1w, h1h, h1l, (float*)nullptr);
  k_qkv_s<<<dim3(QKV_N / 128, S_LEN / 128), 256, 0, stream>>>(h1h, h1l, wqkvPh, wqkvPl, qkvb);
  k_rope2<<<S_LEN, 64, 0, stream>>>(qkvb, qh, ql, kh, kl);
  k_pack2<<<dim3(1, 16, NKV), 256, 0, stream>>>(qkvb + (NH + NKV) * HD, QKV_N, HD, 1,
                                                vPh, vPl);
  for (int c = 0; c < 4; c++) {
    k_qk_s<<<dim3(16, 16, 4), 256, 0, stream>>>(qh, ql, kh, kl, Sh, Sl, 4 * c);
    k_sm_s<<<dim3(S_LEN, 4), 256, 0, stream>>>(Sh, Sl);
    k_pv<<<dim3(4, 16, 4), 256, 0, stream>>>(Sh, Sl, vPh, vPl, pvp, 4 * c);
    k_pvred<<<(4 * S_LEN * 32) / 256, 256, 0, stream>>>(pvp, ath, atl, 4 * c);
  }
  k_wo_s<<<dim3(16, 16), 256, 0, stream>>>(ath, atl, woPh, woPl, x, out);

  // ---- MoE sublayer ----
  k_ln<<<S_LEN, 256, 0, stream>>>(out, ln2w, h2b, (unsigned short*)nullptr, h2f);
  hipMemsetAsync(y, 0, (size_t)S_LEN * DMODEL * 4, stream);
  hipMemsetAsync(meta, 0, 512, stream);
  k_router<<<S_LEN, 256, 0, stream>>>(h2f, rw, topi, topw, meta);
  k_scan<<<1, 64, 0, stream>>>(meta);
  k_fill<<<8, 256, 0, stream>>>(topi, topw, meta, ptok, pw);
  k_pack1<<<dim3(16, 16, NE), 256, 0, stream>>>(w1, FF, (long)DMODEL * FF, 16, wP);
  k_moe_w1<<<dim3(16, 40), 256, 0, stream>>>(h2b, wP, meta + 16, ptok, meta, a1);
  k_pack1<<<dim3(16, 16, NE), 256, 0, stream>>>(v1, FF, (long)DMODEL * FF, 16, wP);
  k_moe_v1g<<<dim3(16, 40), 256, 0, stream>>>(h2b, wP, a1, meta + 16, ptok, meta, g);
  k_pack1<<<dim3(16, 16, NE), 256, 0, stream>>>(w2, DMODEL, (long)FF * DMODEL, 16, wP);
  k_moe2<<<dim3(16, 40), 256, 0, stream>>>(g, wP, meta + 16, ptok, pw, meta, y);
  k_final<<<(S_LEN * DMODEL / 4) / 256, 256, 0, stream>>>(out, y);
}